// Round 12
// baseline (5822.826 us; speedup 1.0000x reference)
//
#include <hip/hip_runtime.h>
#include <hip/hip_bf16.h>

#define DIMS 1024
#define SEQ 512
#define BATCH 128
#define VOCAB 32000
#define GRID 256

typedef __attribute__((ext_vector_type(8))) short short8;
typedef __attribute__((ext_vector_type(4))) float f32x4;

__device__ __forceinline__ ushort f2bf(float x) {
    union { float f; unsigned u; } v; v.f = x;
    unsigned u = v.u;
    return (ushort)((u + 0x7FFFu + ((u >> 16) & 1u)) >> 16);
}

// pack 8 consecutive f32 into a short8 of bf16 (RNE)
__device__ __forceinline__ short8 pack8(const float* p) {
    float4 f0 = *(const float4*)p;
    float4 f1 = *(const float4*)(p + 4);
    union { ushort us[8]; short8 v; } r;
    r.us[0] = f2bf(f0.x); r.us[1] = f2bf(f0.y); r.us[2] = f2bf(f0.z); r.us[3] = f2bf(f0.w);
    r.us[4] = f2bf(f1.x); r.us[5] = f2bf(f1.y); r.us[6] = f2bf(f1.z); r.us[7] = f2bf(f1.w);
    return r.v;
}

// Persistent LSTM, XCD-local h relay, small-workspace edition.
// (R11 hung: its workspace layout needed 70.3MB; R1-R10 fit under 64MiB ->
//  ws_size is likely 64MiB and R11's mirror ran off the end. This version
//  drops the 65.5MB bf16 emb copy — x@W reads f32 emb + packs in-register —
//  so hbuf+ctrl+mirror total ~4.7MB.)
// Structure: R8 homogeneous waves (4 row-quarters x 2 K-halves) plus:
//  x-half1 (hides producer-flag hop) -> relay h chunk into this XCD's L2
//  mirror (plain stores) -> x-half2 (hides xcdfl hop) -> poll xcdfl (agent
//  atomics) -> 16 batched sc0 h-loads from L2 mirror -> h MFMA.
__launch_bounds__(512, 1)
__global__ void lstm_kernel(const int* __restrict__ feats,
                            const float* __restrict__ emb,
                            const float* __restrict__ Wf, const float* __restrict__ Uf, const float* __restrict__ bfp,
                            const float* __restrict__ Wi, const float* __restrict__ Ui, const float* __restrict__ bip,
                            const float* __restrict__ Wo, const float* __restrict__ Uo, const float* __restrict__ bop,
                            const float* __restrict__ Wc, const float* __restrict__ Uc, const float* __restrict__ bcp,
                            ushort* __restrict__ hbuf, float* __restrict__ out,
                            int* __restrict__ flags, int* __restrict__ xcdcnt,
                            int* __restrict__ xcdfl, ushort* __restrict__ xcdbuf) {
    __shared__ ushort Bl[32 * 2048];        // 131072 B: B-slice, XOR-swizzled
    __shared__ float pre0[64 * 36];         // K-half 0 partial (x+h), pitch 36
    __shared__ float pre1[64 * 36];         // K-half 1 partial (x+h)
    __shared__ int s_xcd, s_rank;

    const int tid = threadIdx.x;
    const int bid = blockIdx.x;
    const int rg = bid >> 7;      // row group: rows rg*64 .. rg*64+63
    const int cb = bid & 127;     // d-chunk: d = cb*8 .. cb*8+7

    // ---- one-time: load B slice (f32 -> bf16) into LDS ----
    for (int idx = tid; idx < 32 * 2048; idx += 512) {
        int cl = idx & 31;
        int k  = idx >> 5;
        int g  = cl >> 3, dd0 = cl & 7;
        int dw = cb * 8 + dd0;
        const float* Wg = (g == 0) ? Wf : (g == 1) ? Wi : (g == 2) ? Wo : Wc;
        const float* Ug = (g == 0) ? Uf : (g == 1) ? Ui : (g == 2) ? Uo : Uc;
        float v = (k < 1024) ? Wg[k * 1024 + dw] : Ug[(k - 1024) * 1024 + dw];
        int boff = ((cl << 12) | (k << 1)) ^ ((cl & 7) << 4);
        *(ushort*)((char*)Bl + boff) = f2bf(v);
    }

    // ---- XCD discovery + per-XCD rank election (tid 0) ----
    if (tid == 0) {
        int x;
        asm("s_getreg_b32 %0, hwreg(HW_REG_XCC_ID)" : "=s"(x));
        x &= 7;
        s_xcd = x;
        s_rank = atomicAdd(&xcdcnt[x], 1) & 31;
    }
    __syncthreads();   // Bl + xcd/rank ready
    const int xcd = s_xcd;
    const int rank = s_rank;

    const int lane = tid & 63;
    const int w  = tid >> 6;                 // wave 0..7
    const int wr = w & 3;                    // row quarter: rows wr*16..wr*16+15
    const int kh = w >> 2;                   // K-half: 0 or 1
    const int lx = lane & 15;
    const int qq = lane >> 4;
    const int kg = qq * 8;
    const int lr = wr * 16 + lx;             // local row within row-group
    const int brow = rg * 64 + lr;           // global batch row

    const int bofs0 = (lx << 12) ^ ((lx & 7) << 4);
    const int bofs1 = ((16 + lx) << 12) ^ ((lx & 7) << 4);

    const int kb    = kh * 512;              // K-half base
    const int fbase = kh * 64;               // chunk base (within rg) for h half
    float* myPre = kh ? pre1 : pre0;
    const int r0 = wr * 16 + qq * 4;         // C/D row base

    const int gcw = rank * 8 + w;            // global chunk this wave relays

    // gate-phase mapping: 1 state per thread
    const int grow_ = tid >> 3;
    const int gdd   = tid & 7;
    const int gd    = cb * 8 + gdd;
    const float bF = bfp[gd], bI = bip[gd], bO = bop[gd], bC = bcp[gd];

    float cst = 0.f;
    int fidx = feats[brow * SEQ];

    for (int t = 0; t < SEQ; t++) {
        f32x4 a00 = {0,0,0,0}, a01 = {0,0,0,0};
        f32x4 a10 = {0,0,0,0}, a11 = {0,0,0,0};

        const float* xrow = emb + (size_t)fidx * DIMS;
        fidx = (t + 1 < SEQ) ? feats[brow * SEQ + t + 1] : 0;
        const int par = t & 1;

        // ---- x @ W, my K-half, iters 0..7 (covers producer-flag hop) ----
        #pragma unroll
        for (int ks = 0; ks < 8; ks += 2) {
            {
                int k = kb + ks * 32 + kg;
                short8 a  = pack8(xrow + k);
                short8 b0 = *(const short8*)((const char*)Bl + (bofs0 ^ (k << 1)));
                short8 b1 = *(const short8*)((const char*)Bl + (bofs1 ^ (k << 1)));
                a00 = __builtin_amdgcn_mfma_f32_16x16x32_bf16(a, b0, a00, 0, 0, 0);
                a10 = __builtin_amdgcn_mfma_f32_16x16x32_bf16(a, b1, a10, 0, 0, 0);
            }
            {
                int k = kb + (ks + 1) * 32 + kg;
                short8 a  = pack8(xrow + k);
                short8 b0 = *(const short8*)((const char*)Bl + (bofs0 ^ (k << 1)));
                short8 b1 = *(const short8*)((const char*)Bl + (bofs1 ^ (k << 1)));
                a01 = __builtin_amdgcn_mfma_f32_16x16x32_bf16(a, b0, a01, 0, 0, 0);
                a11 = __builtin_amdgcn_mfma_f32_16x16x32_bf16(a, b1, a11, 0, 0, 0);
            }
        }

        // ---- relay: wave w copies chunk gcw (1KB) into this XCD's mirror ----
        if (t > 0) {
            long guard = 0;
            while (__hip_atomic_load(&flags[gcw], __ATOMIC_RELAXED, __HIP_MEMORY_SCOPE_AGENT) < t) {
                __builtin_amdgcn_s_sleep(1);
                if (++guard > 100000000L) break;  // safety valve
            }
            const unsigned long long* rp = (const unsigned long long*)
                (hbuf + ((size_t)par * 256 + gcw) * 512 + lane * 8);
            union { unsigned long long u[2]; short8 v; } rv;
            rv.u[0] = __hip_atomic_load(rp,     __ATOMIC_RELAXED, __HIP_MEMORY_SCOPE_AGENT);
            rv.u[1] = __hip_atomic_load(rp + 1, __ATOMIC_RELAXED, __HIP_MEMORY_SCOPE_AGENT);
            short8* wp = (short8*)
                (xcdbuf + (((size_t)xcd * 2 + par) * 256 + gcw) * 512 + lane * 8);
            *wp = rv.v;   // plain 16B store -> dirty in local L2
            asm volatile("s_waitcnt vmcnt(0)" ::: "memory");
            __syncthreads();   // all 8 relay chunks of this block are in L2
            if (tid == 0) {
                __hip_atomic_store(&xcdfl[xcd * 32 + rank], t,
                                   __ATOMIC_RELAXED, __HIP_MEMORY_SCOPE_AGENT);
            }
        }

        // ---- x @ W, iters 8..15 (covers xcdfl hop) ----
        #pragma unroll
        for (int ks = 8; ks < 16; ks += 2) {
            {
                int k = kb + ks * 32 + kg;
                short8 a  = pack8(xrow + k);
                short8 b0 = *(const short8*)((const char*)Bl + (bofs0 ^ (k << 1)));
                short8 b1 = *(const short8*)((const char*)Bl + (bofs1 ^ (k << 1)));
                a00 = __builtin_amdgcn_mfma_f32_16x16x32_bf16(a, b0, a00, 0, 0, 0);
                a10 = __builtin_amdgcn_mfma_f32_16x16x32_bf16(a, b1, a10, 0, 0, 0);
            }
            {
                int k = kb + (ks + 1) * 32 + kg;
                short8 a  = pack8(xrow + k);
                short8 b0 = *(const short8*)((const char*)Bl + (bofs0 ^ (k << 1)));
                short8 b1 = *(const short8*)((const char*)Bl + (bofs1 ^ (k << 1)));
                a01 = __builtin_amdgcn_mfma_f32_16x16x32_bf16(a, b0, a01, 0, 0, 0);
                a11 = __builtin_amdgcn_mfma_f32_16x16x32_bf16(a, b1, a11, 0, 0, 0);
            }
        }

        // ---- consume: poll my XCD's 32 xcdfl, then h@U from L2 mirror ----
        if (t > 0) {
            {
                long guard = 0;
                for (;;) {
                    int v = __hip_atomic_load(&xcdfl[xcd * 32 + (lane & 31)],
                                              __ATOMIC_RELAXED, __HIP_MEMORY_SCOPE_AGENT);
                    if (__all(v >= t)) break;
                    __builtin_amdgcn_s_sleep(1);
                    if (++guard > 100000000L) break;  // safety valve
                }
            }
            const ushort* xb = xcdbuf + ((size_t)xcd * 2 + par) * (256 * 512)
                                      + (size_t)rg * (128 * 512);
            short8 hv[16];
            #pragma unroll
            for (int ks = 0; ks < 16; ks++) {
                const ushort* hp = xb + ((fbase + ks * 4 + qq) << 9) + lr * 8;
                asm volatile("global_load_dwordx4 %0, %1, off sc0"
                             : "=v"(hv[ks]) : "v"(hp));   // L1-bypass, L2-hit
            }
            asm volatile("s_waitcnt vmcnt(0)" ::: "memory");
            __builtin_amdgcn_sched_barrier(0);
            #pragma unroll
            for (int ks = 0; ks < 16; ks += 2) {
                {
                    int k = 1024 + kb + ks * 32 + kg;
                    short8 b0 = *(const short8*)((const char*)Bl + (bofs0 ^ (k << 1)));
                    short8 b1 = *(const short8*)((const char*)Bl + (bofs1 ^ (k << 1)));
                    a00 = __builtin_amdgcn_mfma_f32_16x16x32_bf16(hv[ks], b0, a00, 0, 0, 0);
                    a10 = __builtin_amdgcn_mfma_f32_16x16x32_bf16(hv[ks], b1, a10, 0, 0, 0);
                }
                {
                    int k = 1024 + kb + (ks + 1) * 32 + kg;
                    short8 b0 = *(const short8*)((const char*)Bl + (bofs0 ^ (k << 1)));
                    short8 b1 = *(const short8*)((const char*)Bl + (bofs1 ^ (k << 1)));
                    a01 = __builtin_amdgcn_mfma_f32_16x16x32_bf16(hv[ks + 1], b0, a01, 0, 0, 0);
                    a11 = __builtin_amdgcn_mfma_f32_16x16x32_bf16(hv[ks + 1], b1, a11, 0, 0, 0);
                }
            }
        }

        // ---- write partials (C/D layout: col = lane&15, row = (lane>>4)*4 + reg) ----
        #pragma unroll
        for (int j = 0; j < 4; j++) {
            myPre[(r0 + j) * 36 + lx]      = a00[j] + a01[j];
            myPre[(r0 + j) * 36 + 16 + lx] = a10[j] + a11[j];
        }
        __syncthreads();   // sync A: pre0 + pre1 complete

        // ---- gates: 1 state per thread ----
        {
            int base = grow_ * 36;
            float pf = pre0[base + gdd]      + pre1[base + gdd]      + bF;
            float pi = pre0[base + 8 + gdd]  + pre1[base + 8 + gdd]  + bI;
            float po = pre0[base + 16 + gdd] + pre1[base + 16 + gdd] + bO;
            float pc = pre0[base + 24 + gdd] + pre1[base + 24 + gdd] + bC;
            float f  = 1.f / (1.f + __expf(-pf));
            float ig = 1.f / (1.f + __expf(-pi));
            float o  = 1.f / (1.f + __expf(-po));
            float e2 = __expf(2.f * pc);
            float cc = (e2 - 1.f) / (e2 + 1.f);
            float cn = f * cst + ig * cc;
            cst = cn;
            float e2c = __expf(2.f * cn);
            float th  = (e2c - 1.f) / (e2c + 1.f);
            float h   = o * th;
            if (t < SEQ - 1) {
                // publish: hbuf[parity(t+1)][bid][tid], coherent 2B store
                ushort* hw = hbuf + ((size_t)((t + 1) & 1) * 256 + bid) * 512 + tid;
                __hip_atomic_store(hw, f2bf(h), __ATOMIC_RELAXED, __HIP_MEMORY_SCOPE_AGENT);
            } else {
                int gr = rg * 64 + grow_;
                out[gr * 2048 + gd] = h;
                out[gr * 2048 + 1024 + gd] = cn;
            }
        }

        if (t < SEQ - 1) {
            asm volatile("s_waitcnt vmcnt(0)" ::: "memory");  // publish acked at coherence point
            __syncthreads();                                   // sync B
            if (tid == 0) {
                __hip_atomic_store(&flags[bid], t + 1, __ATOMIC_RELAXED, __HIP_MEMORY_SCOPE_AGENT);
            }
        }
    }
}

extern "C" void kernel_launch(void* const* d_in, const int* in_sizes, int n_in,
                              void* d_out, int out_size, void* d_ws, size_t ws_size,
                              hipStream_t stream) {
    const int*   feats = (const int*)d_in[0];
    const float* emb_f = (const float*)d_in[1];
    const float* Wf = (const float*)d_in[2];
    const float* Uf = (const float*)d_in[3];
    const float* bf_ = (const float*)d_in[4];
    const float* Wi = (const float*)d_in[5];
    const float* Ui = (const float*)d_in[6];
    const float* bi_ = (const float*)d_in[7];
    const float* Wo = (const float*)d_in[8];
    const float* Uo = (const float*)d_in[9];
    const float* bo_ = (const float*)d_in[10];
    const float* Wc = (const float*)d_in[11];
    const float* Uc = (const float*)d_in[12];
    const float* bc_ = (const float*)d_in[13];

    char* ws = (char*)d_ws;
    ushort* hbuf   = (ushort*)ws;                 // [2][256][512] bf16 = 524,288 B
    char*   ctrl   = ws + 524288;                 // 4096 B control block
    int*    flags  = (int*)ctrl;                  // 256 ints
    int*    xcdcnt = (int*)(ctrl + 1024);         // 8 ints
    int*    xcdfl  = (int*)(ctrl + 2048);         // 8*32 ints
    ushort* xcdbuf = (ushort*)(ws + 528384);      // [8][2][256][512] bf16 = 4,194,304 B
    // total ws use: 4,722,688 B  (well under the 64MiB R1-R10 footprint)

    hipMemsetAsync(ctrl, 0, 4096, stream);
    lstm_kernel<<<GRID, 512, 0, stream>>>(feats, emb_f,
                                          Wf, Uf, bf_, Wi, Ui, bi_,
                                          Wo, Uo, bo_, Wc, Uc, bc_,
                                          hbuf, (float*)d_out,
                                          flags, xcdcnt, xcdfl, xcdbuf);
}